// Round 3
// baseline (1029.683 us; speedup 1.0000x reference)
//
#include <hip/hip_runtime.h>
#include <hip/hip_bf16.h>
#include <math.h>

typedef __bf16 bf16x8 __attribute__((ext_vector_type(8)));
typedef float  f32x4  __attribute__((ext_vector_type(4)));

#define HDIM   512
#define FLAT   65792
#define DIN    66304
#define G3     1536          // 3*H
#define NSLAB  2056          // FLAT / 32
#define MS     512           // Mbuf row stride (N = 512 exactly now)
#define KSPLIT 21
#define CHUNK  98            // slabs per K chunk (21*98 = 2058 >= 2056)

// workspace layout (bytes)
#define BH_BYTES   67371008ULL  // NSLAB * 32 * 512 * 2  (frag-packed bf16 B)
#define MBUF_BYTES  3145728ULL  // G3*MS*4
#define BP_BYTES       6144ULL  // G3*4
#define ST_BYTES       6144ULL  // G3*4
#define GIB_BYTES    393216ULL  // 64*G3*4
#define HALL_BYTES   131072ULL  // 64*512*4
#define HBF_BYTES     65536ULL  // 64*512*2

__device__ __forceinline__ ushort f2bf(float f) {
    uint u = __float_as_uint(f);
    u += 0x7FFFu + ((u >> 16) & 1u);   // round-to-nearest-even
    return (ushort)(u >> 16);
}
__device__ __forceinline__ uint pk2(float a, float b) {
    return (uint)f2bf(a) | ((uint)f2bf(b) << 16);
}

// ---------------------------------------------------------------------------
// K1: pack B = W_proj into per-lane MFMA B-fragment layout, bf16.
// Frag for (slab s, n-tile t, lane): 8 values j=0..7 = Wp[s*32+quad*8+j][t*16+lrow]
// stored as uint4 at Bh + s*32768B + t*1024B + lane*16B.
// No LDS: loads coalesce at 64B/row granularity; every input byte read once.
// ---------------------------------------------------------------------------
__global__ __launch_bounds__(256) void buildBh(const float* __restrict__ Wp,
                                               ushort* __restrict__ Bh) {
    const int s    = blockIdx.x;          // slab 0..2055
    const int lane = threadIdx.x & 63;
    const int wave = threadIdx.x >> 6;    // 0..3
    const int lrow = lane & 15;
    const int quad = lane >> 4;
    const float* base = Wp + (size_t)s * 32 * 512;   // rows s*32 .. s*32+31
    ushort* out = Bh + (size_t)s * 16384;            // ushort units
#pragma unroll
    for (int i = 0; i < 8; ++i) {
        const int t = wave + i * 4;       // 0..31
        const int col = t * 16 + lrow;
        float v[8];
#pragma unroll
        for (int j = 0; j < 8; ++j)
            v[j] = base[(size_t)(quad * 8 + j) * 512 + col];
        uint4 pr;
        pr.x = pk2(v[0], v[1]);
        pr.y = pk2(v[2], v[3]);
        pr.z = pk2(v[4], v[5]);
        pr.w = pk2(v[6], v[7]);
        *(uint4*)(out + (size_t)t * 512 + (size_t)lane * 8) = pr;
    }
}

// ---------------------------------------------------------------------------
// K2: M = W_ih[:,512:] @ W_proj  (1536 x 512), split-K, LDS-FREE.
// 512 thr = 8 waves (2Mg x 4Ng); wave C-tile 64M x 128N (4 Mfrag x 8 Nfrag).
// A fp32 direct from global in frag layout (in-register bf16 cvt, 1-slab
// prefetch); B bf16 direct from frag-packed Bh. fp32 atomicAdd epilogue.
// ng==0 waves also fold bp = A@b_proj, st = A@start in fp32 on the A regs.
// ---------------------------------------------------------------------------
__global__ __launch_bounds__(512, 2) void gemmM(const float* __restrict__ Wih,
                                                const ushort* __restrict__ Bh,
                                                const float* __restrict__ bproj,
                                                const float* __restrict__ start,
                                                float* __restrict__ Mbuf,
                                                float* __restrict__ bpA,
                                                float* __restrict__ stA) {
    const int tid  = threadIdx.x;
    const int lane = tid & 63;
    const int wave = tid >> 6;        // 0..7
    const int mg   = wave >> 2;       // 0..1
    const int ng   = wave & 3;        // 0..3
    const int lrow = lane & 15;
    const int quad = lane >> 4;
    const int mtile = blockIdx.x % 12;
    const int kc    = blockIdx.x / 12;
    const int s0 = kc * CHUNK;
    const int s1 = min(s0 + CHUNK, NSLAB);

    const int rowBase = mtile * 128 + mg * 64 + lrow;   // + mf*16
    const float* aP[4];
#pragma unroll
    for (int mf = 0; mf < 4; ++mf)
        aP[mf] = Wih + (size_t)(rowBase + mf * 16) * DIN + 512 + quad * 8;
    const ushort* bBase = Bh + (size_t)(ng * 8) * 512 + (size_t)lane * 8;

    f32x4 acc[4][8];
#pragma unroll
    for (int mf = 0; mf < 4; ++mf)
#pragma unroll
        for (int nf = 0; nf < 8; ++nf) acc[mf][nf] = (f32x4){0.f, 0.f, 0.f, 0.f};
    float bpAcc[4] = {0.f, 0.f, 0.f, 0.f};
    float stAcc[4] = {0.f, 0.f, 0.f, 0.f};

    float4 a0[4], a1[4];
#pragma unroll
    for (int mf = 0; mf < 4; ++mf) {
        a0[mf] = *(const float4*)(aP[mf] + (size_t)s0 * 32);
        a1[mf] = *(const float4*)(aP[mf] + (size_t)s0 * 32 + 4);
    }

    for (int s = s0; s < s1; ++s) {
        // B fragments for this slab (L2/LLC-served)
        uint4 bReg[8];
        const ushort* bs = bBase + (size_t)s * 16384;
#pragma unroll
        for (int nf = 0; nf < 8; ++nf)
            bReg[nf] = *(const uint4*)(bs + nf * 512);
        // fp32 side-dots for the b_proj / start columns (dedup: ng==0 only)
        if (ng == 0) {
            const float4 bp0 = *(const float4*)(bproj + s * 32 + quad * 8);
            const float4 bp1 = *(const float4*)(bproj + s * 32 + quad * 8 + 4);
            const float4 st0 = *(const float4*)(start + s * 32 + quad * 8);
            const float4 st1 = *(const float4*)(start + s * 32 + quad * 8 + 4);
#pragma unroll
            for (int mf = 0; mf < 4; ++mf) {
                bpAcc[mf] += a0[mf].x * bp0.x + a0[mf].y * bp0.y + a0[mf].z * bp0.z + a0[mf].w * bp0.w
                           + a1[mf].x * bp1.x + a1[mf].y * bp1.y + a1[mf].z * bp1.z + a1[mf].w * bp1.w;
                stAcc[mf] += a0[mf].x * st0.x + a0[mf].y * st0.y + a0[mf].z * st0.z + a0[mf].w * st0.w
                           + a1[mf].x * st1.x + a1[mf].y * st1.y + a1[mf].z * st1.z + a1[mf].w * st1.w;
            }
        }
        // cvt A to bf16 fragments
        bf16x8 af[4];
#pragma unroll
        for (int mf = 0; mf < 4; ++mf) {
            uint4 pr;
            pr.x = pk2(a0[mf].x, a0[mf].y);
            pr.y = pk2(a0[mf].z, a0[mf].w);
            pr.z = pk2(a1[mf].x, a1[mf].y);
            pr.w = pk2(a1[mf].z, a1[mf].w);
            af[mf] = __builtin_bit_cast(bf16x8, pr);
        }
        // prefetch next slab's A (in flight under the MFMAs)
        if (s + 1 < s1) {
#pragma unroll
            for (int mf = 0; mf < 4; ++mf) {
                a0[mf] = *(const float4*)(aP[mf] + (size_t)(s + 1) * 32);
                a1[mf] = *(const float4*)(aP[mf] + (size_t)(s + 1) * 32 + 4);
            }
        }
#pragma unroll
        for (int nf = 0; nf < 8; ++nf) {
            const bf16x8 bf = __builtin_bit_cast(bf16x8, bReg[nf]);
#pragma unroll
            for (int mf = 0; mf < 4; ++mf)
                acc[mf][nf] = __builtin_amdgcn_mfma_f32_16x16x32_bf16(af[mf], bf, acc[mf][nf], 0, 0, 0);
        }
    }
    // epilogue: split-K accumulate
#pragma unroll
    for (int mf = 0; mf < 4; ++mf)
#pragma unroll
        for (int nf = 0; nf < 8; ++nf) {
            const int col = (ng * 8 + nf) * 16 + lrow;
#pragma unroll
            for (int r = 0; r < 4; ++r) {
                const int row = mtile * 128 + mg * 64 + mf * 16 + quad * 4 + r;
                atomicAdd(&Mbuf[(size_t)row * MS + col], acc[mf][nf][r]);
            }
        }
    if (ng == 0) {
#pragma unroll
        for (int mf = 0; mf < 4; ++mf) {
            float bp = bpAcc[mf], st = stAcc[mf];
            bp += __shfl_xor(bp, 16); bp += __shfl_xor(bp, 32);
            st += __shfl_xor(st, 16); st += __shfl_xor(st, 32);
            if (lane < 16) {
                atomicAdd(&bpA[rowBase + mf * 16], bp);
                atomicAdd(&stA[rowBase + mf * 16], st);
            }
        }
    }
}

// ---------------------------------------------------------------------------
// K3: gi_base[pair][j] = b_ih[j] + W_ih[j,:256]@content[b,s] + W_ih[j,256:512]@style[b]
//                        + (s==0 ? st[j] : bp[j])
// ---------------------------------------------------------------------------
__global__ __launch_bounds__(256) void giBase(const float* __restrict__ Wih,
                                              const float* __restrict__ content,
                                              const float* __restrict__ style,
                                              const float* __restrict__ bih,
                                              const float* __restrict__ bpA,
                                              const float* __restrict__ stA,
                                              float* __restrict__ giB) {
    const int j = (blockIdx.x * blockDim.x + threadIdx.x) >> 6;
    if (j >= G3) return;
    const int lane = threadIdx.x & 63;   // pair = b*16 + s
    const int b = lane >> 4;
    const int s = lane & 15;
    const float* wr = Wih + (size_t)j * DIN;
    const float* cp = content + (size_t)lane * 256;
    const float* sp = style + (size_t)b * 256;
    float acc = 0.f;
#pragma unroll 4
    for (int d = 0; d < 256; d += 4) {
        const float4 w = *(const float4*)(wr + d);
        const float4 x = *(const float4*)(cp + d);
        acc += w.x * x.x + w.y * x.y + w.z * x.z + w.w * x.w;
    }
#pragma unroll 4
    for (int d = 0; d < 256; d += 4) {
        const float4 w = *(const float4*)(wr + 256 + d);
        const float4 x = *(const float4*)(sp + d);
        acc += w.x * x.x + w.y * x.y + w.z * x.z + w.w * x.w;
    }
    acc += bih[j] + ((s == 0) ? stA[j] : bpA[j]);
    giB[(size_t)lane * G3 + j] = acc;
}

// ---------------------------------------------------------------------------
// K4 (x16): one GRU step. Wave per (b, j): six 512-length dots, shuffle-reduce.
// ---------------------------------------------------------------------------
__global__ __launch_bounds__(256) void stepK(const float* __restrict__ Mbuf,
                                             const float* __restrict__ Whh,
                                             const float* __restrict__ bhh,
                                             const float* __restrict__ giB,
                                             float* __restrict__ hAll,
                                             ushort* __restrict__ hBf,
                                             const int s) {
    const int gw   = (blockIdx.x * blockDim.x + threadIdx.x) >> 6;  // 0..2047
    const int lane = threadIdx.x & 63;
    const int b = gw & 3;
    const int j = gw >> 2;          // 0..511
    float dMr = 0.f, dMz = 0.f, dMn = 0.f, dWr = 0.f, dWz = 0.f, dWn = 0.f;
    if (s > 0) {
        const float* h = hAll + (size_t)((s - 1) * 4 + b) * HDIM;
        float hr[8];
#pragma unroll
        for (int i = 0; i < 8; ++i) hr[i] = h[i * 64 + lane];
        const float* M0 = Mbuf + (size_t)j * MS;
        const float* M1 = Mbuf + (size_t)(j + 512) * MS;
        const float* M2 = Mbuf + (size_t)(j + 1024) * MS;
        const float* W0 = Whh + (size_t)j * HDIM;
        const float* W1 = Whh + (size_t)(j + 512) * HDIM;
        const float* W2 = Whh + (size_t)(j + 1024) * HDIM;
#pragma unroll
        for (int i = 0; i < 8; ++i) {
            const int d = i * 64 + lane;
            dMr += M0[d] * hr[i]; dMz += M1[d] * hr[i]; dMn += M2[d] * hr[i];
            dWr += W0[d] * hr[i]; dWz += W1[d] * hr[i]; dWn += W2[d] * hr[i];
        }
#pragma unroll
        for (int m = 1; m < 64; m <<= 1) {
            dMr += __shfl_xor(dMr, m); dMz += __shfl_xor(dMz, m); dMn += __shfl_xor(dMn, m);
            dWr += __shfl_xor(dWr, m); dWz += __shfl_xor(dWz, m); dWn += __shfl_xor(dWn, m);
        }
    }
    if (lane == 0) {
        const float* gb = giB + (size_t)(b * 16 + s) * G3;
        const float gir = gb[j] + dMr;
        const float giz = gb[j + 512] + dMz;
        const float gin = gb[j + 1024] + dMn;
        const float ghr = bhh[j] + dWr;
        const float ghz = bhh[j + 512] + dWz;
        const float ghn = bhh[j + 1024] + dWn;
        const float r = 1.f / (1.f + expf(-(gir + ghr)));
        const float z = 1.f / (1.f + expf(-(giz + ghz)));
        const float n = tanhf(gin + r * ghn);
        const float hp = (s > 0) ? hAll[(size_t)((s - 1) * 4 + b) * HDIM + j] : 0.f;
        const float hn = (1.f - z) * n + z * hp;
        hAll[(size_t)(s * 4 + b) * HDIM + j] = hn;
        hBf[(size_t)(s * 4 + b) * HDIM + j] = f2bf(hn);
    }
}

// ---------------------------------------------------------------------------
// K5: out[b][s][f] = W_proj[f] . h[s*4+b] + b_proj[f], MFMA bf16.
// ---------------------------------------------------------------------------
__global__ __launch_bounds__(256) void projK(const float* __restrict__ Wp,
                                             const float* __restrict__ bproj,
                                             const ushort* __restrict__ hBf,
                                             float* __restrict__ out) {
    const int lane = threadIdx.x & 63;
    const int wave = threadIdx.x >> 6;
    const int f0   = blockIdx.x * 256 + wave * 64;
    const int lrow = lane & 15;
    const int quad = lane >> 4;
    f32x4 acc[4][4];
#pragma unroll
    for (int pt = 0; pt < 4; ++pt)
#pragma unroll
        for (int ft = 0; ft < 4; ++ft) acc[pt][ft] = (f32x4){0.f, 0.f, 0.f, 0.f};

    for (int d0 = 0; d0 < HDIM; d0 += 32) {
        bf16x8 afr[4];
#pragma unroll
        for (int pt = 0; pt < 4; ++pt)
            afr[pt] = __builtin_bit_cast(bf16x8,
                *(const uint4*)(hBf + (size_t)(pt * 16 + lrow) * HDIM + d0 + quad * 8));
#pragma unroll
        for (int ft = 0; ft < 4; ++ft) {
            const float* wrow = Wp + (size_t)(f0 + ft * 16 + lrow) * HDIM + d0 + quad * 8;
            const float4 w0 = *(const float4*)(wrow);
            const float4 w1 = *(const float4*)(wrow + 4);
            uint4 pr;
            pr.x = pk2(w0.x, w0.y);
            pr.y = pk2(w0.z, w0.w);
            pr.z = pk2(w1.x, w1.y);
            pr.w = pk2(w1.z, w1.w);
            const bf16x8 bfr = __builtin_bit_cast(bf16x8, pr);
#pragma unroll
            for (int pt = 0; pt < 4; ++pt)
                acc[pt][ft] = __builtin_amdgcn_mfma_f32_16x16x32_bf16(afr[pt], bfr, acc[pt][ft], 0, 0, 0);
        }
    }
#pragma unroll
    for (int pt = 0; pt < 4; ++pt)
#pragma unroll
        for (int ft = 0; ft < 4; ++ft) {
            const int f = f0 + ft * 16 + lrow;
            const float bp = bproj[f];
#pragma unroll
            for (int r = 0; r < 4; ++r) {
                const int p = pt * 16 + quad * 4 + r;   // pair index = s*4 + b
                const int ss = p >> 2;
                const int bb = p & 3;
                out[(size_t)(bb * 16 + ss) * FLAT + f] = acc[pt][ft][r] + bp;
            }
        }
}

// ---------------------------------------------------------------------------
extern "C" void kernel_launch(void* const* d_in, const int* in_sizes, int n_in,
                              void* d_out, int out_size, void* d_ws, size_t ws_size,
                              hipStream_t stream) {
    const float* content = (const float*)d_in[0];  // (4,16,256)
    const float* style   = (const float*)d_in[1];  // (4,256)
    const float* start   = (const float*)d_in[2];  // (65792)
    const float* Wih     = (const float*)d_in[3];  // (1536, 66304)
    const float* Whh     = (const float*)d_in[4];  // (1536, 512)
    const float* bih     = (const float*)d_in[5];  // (1536)
    const float* bhh     = (const float*)d_in[6];  // (1536)
    const float* Wproj   = (const float*)d_in[7];  // (65792, 512)
    const float* bproj   = (const float*)d_in[8];  // (65792)
    float* out = (float*)d_out;

    char* ws = (char*)d_ws;
    ushort* Bh   = (ushort*)(ws);
    float*  Mbuf = (float*)(ws + BH_BYTES);
    float*  bpA  = (float*)(ws + BH_BYTES + MBUF_BYTES);
    float*  stA  = (float*)(ws + BH_BYTES + MBUF_BYTES + BP_BYTES);
    float*  giB  = (float*)(ws + BH_BYTES + MBUF_BYTES + BP_BYTES + ST_BYTES);
    float*  hAll = (float*)(ws + BH_BYTES + MBUF_BYTES + BP_BYTES + ST_BYTES + GIB_BYTES);
    ushort* hBf  = (ushort*)(ws + BH_BYTES + MBUF_BYTES + BP_BYTES + ST_BYTES + GIB_BYTES + HALL_BYTES);

    // zero Mbuf + bpA + stA in one contiguous memset
    hipMemsetAsync(Mbuf, 0, MBUF_BYTES + BP_BYTES + ST_BYTES, stream);
    buildBh<<<NSLAB, 256, 0, stream>>>(Wproj, Bh);
    gemmM<<<12 * KSPLIT, 512, 0, stream>>>(Wih, Bh, bproj, start, Mbuf, bpA, stA);
    giBase<<<384, 256, 0, stream>>>(Wih, content, style, bih, bpA, stA, giB);
    for (int s = 0; s < 16; ++s)
        stepK<<<512, 256, 0, stream>>>(Mbuf, Whh, bhh, giB, hAll, hBf, s);
    projK<<<FLAT / 256, 256, 0, stream>>>(Wproj, bproj, hBf, out);
}